// Round 17
// baseline (392.454 us; speedup 1.0000x reference)
//
#include <hip/hip_runtime.h>

#define B_  2
#define S_  2048
#define D_  1024
#define H_  16
#define KV_ 8
#define HD_ 128
#define FF_ 3072
#define KVB 32

typedef short bf16x8 __attribute__((ext_vector_type(8)));
typedef short bf16x4 __attribute__((ext_vector_type(4)));
typedef float f32x4 __attribute__((ext_vector_type(4)));

__device__ __forceinline__ float bf2f(unsigned short u) {
    union { float f; unsigned int i; } c; c.i = ((unsigned int)u) << 16; return c.f;
}
__device__ __forceinline__ unsigned short f2bf(float f) {
    union { float f; unsigned int i; } c; c.f = f;
    unsigned int r = c.i + 0x7fffu + ((c.i >> 16) & 1u);
    return (unsigned short)(r >> 16);
}
__device__ __forceinline__ unsigned int cvtpk_bf16(float lo, float hi) {
    unsigned int r;
    asm("v_cvt_pk_bf16_f32 %0, %1, %2" : "=v"(r) : "v"(lo), "v"(hi));
    return r;
}

__device__ __forceinline__ void gload_lds16(const unsigned short* g, char* ldsbase) {
    __builtin_amdgcn_global_load_lds(
        (const __attribute__((address_space(1))) unsigned int*)g,
        (__attribute__((address_space(3))) unsigned int*)ldsbase, 16, 0, 0);
}

__device__ __forceinline__ f32x4 pv_mfma(bf16x4 a, bf16x4 b, f32x4 c) {
#if __has_builtin(__builtin_amdgcn_mfma_f32_16x16x16bf16_1k)
    return __builtin_amdgcn_mfma_f32_16x16x16bf16_1k(a, b, c, 0, 0, 0);
#elif __has_builtin(__builtin_amdgcn_mfma_f32_16x16x16_bf16)
    return __builtin_amdgcn_mfma_f32_16x16x16_bf16(a, b, c, 0, 0, 0);
#else
    f32x4 d;
    asm("v_mfma_f32_16x16x16_bf16 %0, %1, %2, %3" : "=v"(d) : "v"(a), "v"(b), "v"(c));
    return d;
#endif
}

// ---------------- rmsnorm: fp32 in -> bf16 out, D=1024, one block per row ----------------
__global__ __launch_bounds__(256)
void rmsnorm_kernel(const float* __restrict__ in, const float* __restrict__ scale,
                    unsigned short* __restrict__ out) {
    const int row = blockIdx.x;
    const int t = threadIdx.x;
    const float4 v = *reinterpret_cast<const float4*>(in + (size_t)row * D_ + t * 4);
    float s = v.x * v.x + v.y * v.y + v.z * v.z + v.w * v.w;
    #pragma unroll
    for (int o = 32; o; o >>= 1) s += __shfl_down(s, o);
    __shared__ float red[4];
    const int lane = t & 63, wid = t >> 6;
    if (lane == 0) red[wid] = s;
    __syncthreads();
    s = red[0] + red[1] + red[2] + red[3];
    const float rn = rsqrtf(s * (1.0f / D_) + 1e-6f);
    const float4 sc = *reinterpret_cast<const float4*>(scale + t * 4);
    unsigned short o4[4];
    o4[0] = f2bf(v.x * rn * sc.x);
    o4[1] = f2bf(v.y * rn * sc.y);
    o4[2] = f2bf(v.z * rn * sc.z);
    o4[3] = f2bf(v.w * rn * sc.w);
    *reinterpret_cast<ushort4*>(out + (size_t)row * D_ + t * 4) =
        *reinterpret_cast<ushort4*>(o4);
}

// ---------------- batched weight transpose: 7 weights, one launch ----------------
struct WTDesc {
    const float* src[7];
    unsigned short* dst[7];
    int K[7];
    int N[7];
    int start[8];
};

__global__ __launch_bounds__(256)
void wtrans_all_kernel(WTDesc d) {
    __shared__ float tile[32][33];
    const int blk = blockIdx.x;
    int i = 0;
    #pragma unroll
    for (int j = 0; j < 7; ++j) if (blk >= d.start[j + 1]) i = j + 1;
    const int local = blk - d.start[i];
    const int K = d.K[i], N = d.N[i];
    const int nkt = K >> 5;
    const int kt = (local % nkt) * 32, nt = (local / nkt) * 32;
    const float* W = d.src[i];
    unsigned short* Wt = d.dst[i];
    const int t = threadIdx.x;
    {
        const int r = t >> 3, c4 = (t & 7) * 4;
        const float4 v = *reinterpret_cast<const float4*>(W + (size_t)(kt + r) * N + nt + c4);
        tile[r][c4] = v.x; tile[r][c4 + 1] = v.y; tile[r][c4 + 2] = v.z; tile[r][c4 + 3] = v.w;
    }
    __syncthreads();
    {
        const int n = t >> 3, k4 = (t & 7) * 4;
        unsigned short o[4];
        #pragma unroll
        for (int q = 0; q < 4; q++) o[q] = f2bf(tile[k4 + q][n]);
        *reinterpret_cast<ushort4*>(Wt + (size_t)(nt + n) * K + kt + k4) =
            *reinterpret_cast<ushort4*>(o);
    }
}

// ---------------- V transpose: vin[m][n] (ld 4096) -> vt[n][m] (ld 4096), bf16 ----------
__global__ __launch_bounds__(256)
void vtrans_kernel(const unsigned short* __restrict__ vin, unsigned short* __restrict__ vt) {
    __shared__ unsigned short tile[32][36];
    const int t = threadIdx.x;
    const int mt = blockIdx.x * 32, nt = blockIdx.y * 32;
    {
        const int r = t >> 3, c4 = (t & 7) * 4;
        *reinterpret_cast<ushort4*>(&tile[r][c4]) =
            *reinterpret_cast<const ushort4*>(vin + (size_t)(mt + r) * 4096 + nt + c4);
    }
    __syncthreads();
    {
        const int n = t >> 3, m4 = (t & 7) * 4;
        unsigned short o[4];
        #pragma unroll
        for (int q = 0; q < 4; q++) o[q] = tile[m4 + q][n];
        *reinterpret_cast<ushort4*>(vt + (size_t)(nt + n) * 4096 + mt + m4) =
            *reinterpret_cast<ushort4*>(o);
    }
}

// =============== 256^2 GEMM, 2-phase counted-vmcnt pipeline (verified round 8) ===========
__global__ __launch_bounds__(512, 2)
void gemm256(const unsigned short* __restrict__ A, const unsigned short* __restrict__ Bt,
             unsigned short* __restrict__ C, int M, int N, int K, int nm) {
    __shared__ __align__(16) char lds[131072];
    const int tid = threadIdx.x;
    const int lane = tid & 63, w = tid >> 6;
    const int lm = lane & 15, lg = lane >> 4;
    const int wr = w >> 2, wc = w & 3;
    const int nwg = gridDim.x;
    const int cpx = nwg >> 3;                         // nwg % 8 == 0 (caller guarantees)
    const int bid = blockIdx.x;
    const int swz = (bid & 7) * cpx + (bid >> 3);     // bijective XCD swizzle
    const int m0 = (swz % nm) * 256;
    const int n0 = (swz / nm) * 256;

    f32x4 acc[8][4];
    #pragma unroll
    for (int i = 0; i < 8; ++i)
        #pragma unroll
        for (int j = 0; j < 4; ++j) acc[i][j] = (f32x4){0.f, 0.f, 0.f, 0.f};

    const int srow = tid >> 3;                                     // 0..63
    const int skel = ((tid & 7) * 8) ^ (((tid >> 5) & 1) << 4);    // pre-swizzled k-elem
    const int flip = ((lm >> 2) & 1) << 5;                         // read-side swizzle
    const int abase = (wr * 128 + lm) * 128 + ((lg * 16) ^ flip);
    const int bbase = (wc * 64 + lm) * 128 + ((lg * 16) ^ flip);

    auto part1 = [&](int kt, int d) {   // B0,B1,B2,B3,A0,A2 — issue order pinned
        const unsigned short* ga = A + (size_t)(m0 + srow) * K + kt * 64 + skel;
        const unsigned short* gb = Bt + (size_t)(n0 + srow) * K + kt * 64 + skel;
        char* la = lds + d * 65536 + (w << 10);
        char* lb = la + 32768;
        gload_lds16(gb,                      lb);
        gload_lds16(gb + (size_t)64 * K,     lb + 8192);
        gload_lds16(gb + (size_t)128 * K,    lb + 16384);
        gload_lds16(gb + (size_t)192 * K,    lb + 24576);
        gload_lds16(ga,                      la);
        gload_lds16(ga + (size_t)128 * K,    la + 16384);
    };
    auto part2 = [&](int kt, int d) {   // A1,A3
        const unsigned short* ga = A + (size_t)(m0 + srow) * K + kt * 64 + skel;
        char* la = lds + d * 65536 + (w << 10);
        gload_lds16(ga + (size_t)64 * K,     la + 8192);
        gload_lds16(ga + (size_t)192 * K,    la + 24576);
    };

    part1(0, 0);
    part2(0, 0);
    asm volatile("s_waitcnt vmcnt(0)" ::: "memory");
    __builtin_amdgcn_s_barrier();

    const int ntile = K >> 6;
    for (int kt = 0; kt < ntile; ++kt) {
        const int d = kt & 1;
        const bool pf = (kt + 1 < ntile);
        const char* Ar = lds + d * 65536;
        const char* Br = Ar + 32768;
        bf16x8 bb[4][2];
        #pragma unroll
        for (int nf = 0; nf < 4; ++nf)
            #pragma unroll
            for (int s = 0; s < 2; ++s)
                bb[nf][s] = *reinterpret_cast<const bf16x8*>(Br + bbase + nf * 2048 + s * 64);
        bf16x8 aH[4][2];
        #pragma unroll
        for (int f = 0; f < 4; ++f)
            #pragma unroll
            for (int s = 0; s < 2; ++s)
                aH[f][s] = *reinterpret_cast<const bf16x8*>(Ar + abase + f * 2048 + s * 64);
        if (pf) part1(kt + 1, d ^ 1);
        __builtin_amdgcn_s_setprio(1);
        #pragma unroll
        for (int f = 0; f < 4; ++f)
            #pragma unroll
            for (int nf = 0; nf < 4; ++nf)
                #pragma unroll
                for (int s = 0; s < 2; ++s)
                    acc[f][nf] = __builtin_amdgcn_mfma_f32_16x16x32_bf16(
                        aH[f][s], bb[nf][s], acc[f][nf], 0, 0, 0);
        __builtin_amdgcn_s_setprio(0);
        if (pf) asm volatile("s_waitcnt vmcnt(6)" ::: "memory");
        else    asm volatile("s_waitcnt vmcnt(0)" ::: "memory");
        __builtin_amdgcn_s_barrier();
        #pragma unroll
        for (int f = 0; f < 4; ++f)
            #pragma unroll
            for (int s = 0; s < 2; ++s)
                aH[f][s] = *reinterpret_cast<const bf16x8*>(Ar + abase + 8192 + f * 2048 + s * 64);
        if (pf) part2(kt + 1, d ^ 1);
        __builtin_amdgcn_s_setprio(1);
        #pragma unroll
        for (int f = 0; f < 4; ++f)
            #pragma unroll
            for (int nf = 0; nf < 4; ++nf)
                #pragma unroll
                for (int s = 0; s < 2; ++s)
                    acc[4 + f][nf] = __builtin_amdgcn_mfma_f32_16x16x32_bf16(
                        aH[f][s], bb[nf][s], acc[4 + f][nf], 0, 0, 0);
        __builtin_amdgcn_s_setprio(0);
        if (pf) {
            asm volatile("s_waitcnt vmcnt(2)" ::: "memory");
            __builtin_amdgcn_s_barrier();
        }
    }

    #pragma unroll
    for (int mf = 0; mf < 8; ++mf)
        #pragma unroll
        for (int nf = 0; nf < 4; ++nf)
            #pragma unroll
            for (int r = 0; r < 4; ++r)
                C[(size_t)(m0 + wr * 128 + mf * 16 + lg * 4 + r) * N +
                  (n0 + wc * 64 + nf * 16 + lm)] = f2bf(acc[mf][nf][r]);
}

// ---------------- m97-structure GEMM: C[M,N] = A(bf16 [M][lda]) @ Bt(bf16 [N][K])^T ------
template<int EPI>
__global__ __launch_bounds__(256)
void gemm_bt(const unsigned short* __restrict__ A, const unsigned short* __restrict__ Bt,
             void* __restrict__ Cout, const float* __restrict__ resid,
             int M, int N, int K, int lda) {
    __shared__ __align__(16) char sm[16384];
    const int t = threadIdx.x;
    const int lane = t & 63, w = t >> 6;
    const int m0 = blockIdx.x * 128, n0 = blockIdx.y * 128;
    const int wr = w >> 1, wc = w & 1;
    const int lm = lane & 15, lg = lane >> 4;

    f32x4 acc[4][4];
    #pragma unroll
    for (int i = 0; i < 4; i++)
        #pragma unroll
        for (int j = 0; j < 4; j++) acc[i][j] = (f32x4){0.f, 0.f, 0.f, 0.f};

    const int row0 = t >> 2, kseg = (t & 3) * 8;
    const unsigned short* Ab = A + (size_t)(m0 + row0) * lda + kseg;
    const unsigned short* Bb = Bt + (size_t)(n0 + row0) * K + kseg;
    const size_t rstepA = (size_t)64 * lda;
    const size_t rstepB = (size_t)64 * K;
    char* ldsA = sm + w * 1024;
    char* ldsB = sm + 8192 + w * 1024;

    for (int k0 = 0; k0 < K; k0 += 32) {
        gload_lds16(Ab + k0, ldsA);
        gload_lds16(Ab + rstepA + k0, ldsA + 4096);
        gload_lds16(Bb + k0, ldsB);
        gload_lds16(Bb + rstepB + k0, ldsB + 4096);
        __syncthreads();
        bf16x8 aF[4], bF[4];
        #pragma unroll
        for (int i = 0; i < 4; i++)
            aF[i] = *reinterpret_cast<const bf16x8*>(sm + (wr * 64 + i * 16 + lm) * 64 + lg * 16);
        #pragma unroll
        for (int j = 0; j < 4; j++)
            bF[j] = *reinterpret_cast<const bf16x8*>(sm + 8192 + (wc * 64 + j * 16 + lm) * 64 + lg * 16);
        #pragma unroll
        for (int i = 0; i < 4; i++)
            #pragma unroll
            for (int j = 0; j < 4; j++)
                acc[i][j] = __builtin_amdgcn_mfma_f32_16x16x32_bf16(aF[i], bF[j], acc[i][j], 0, 0, 0);
        __syncthreads();
    }

    #pragma unroll
    for (int i = 0; i < 4; i++) {
        #pragma unroll
        for (int j = 0; j < 4; j++) {
            #pragma unroll
            for (int r = 0; r < 4; r++) {
                const int row = m0 + wr * 64 + i * 16 + lg * 4 + r;
                const int col = n0 + wc * 64 + j * 16 + lm;
                const size_t idx = (size_t)row * N + col;
                if (EPI == 0) {
                    reinterpret_cast<unsigned short*>(Cout)[idx] = f2bf(acc[i][j][r]);
                } else {
                    reinterpret_cast<float*>(Cout)[idx] = resid[idx] + acc[i][j][r];
                }
            }
        }
    }
}

// ---------------- per-head rmsnorm + rope, in-place, with output scale ----------------
__global__ __launch_bounds__(128)
void qknorm_rope_kernel(unsigned short* __restrict__ qk, const float* __restrict__ scale,
                        const float* __restrict__ cosb, const float* __restrict__ sinb,
                        int ld, float oscale) {
    const int row = blockIdx.x;
    const int head = blockIdx.y;
    const int s = row & (S_ - 1);
    const int t = threadIdx.x;
    unsigned short* p = qk + (size_t)row * ld + head * HD_;
    const float v = bf2f(p[t]);
    float ss = v * v;
    #pragma unroll
    for (int o = 32; o; o >>= 1) ss += __shfl_down(ss, o);
    __shared__ float red[2];
    __shared__ float vals[HD_];
    const int lane = t & 63, wid = t >> 6;
    if (lane == 0) red[wid] = ss;
    __syncthreads();
    ss = red[0] + red[1];
    const float rn = rsqrtf(ss * (1.0f / HD_) + 1e-6f);
    const float nv = v * rn * scale[t];
    vals[t] = nv;
    __syncthreads();
    const float rot = (t < 64) ? -vals[t + 64] : vals[t - 64];
    const float c = cosb[(size_t)s * HD_ + t];
    const float sn = sinb[(size_t)s * HD_ + t];
    p[t] = f2bf((nv * c + rot * sn) * oscale);
}

// ---------------- MFMA flash attention v3: VALU-diet (cvt_pk + log2-domain Q) ----------
// Q pre-scaled by log2(e)/sqrt(128) at rope time -> scores in log2 domain; exp2 direct.
__global__ __launch_bounds__(256)
void fattn_kernel(const unsigned short* __restrict__ qg,
                  const unsigned short* __restrict__ kg,
                  const unsigned short* __restrict__ vtg,
                  unsigned short* __restrict__ out, int qld, int kld) {
    __shared__ __align__(16) char klds[2 * 8192];    // [buf][32 rows x 256B], xor-swizzled
    __shared__ __align__(16) char vtlds[2 * 9216];   // [buf][128 rows x 72B pitch]
    const int t = threadIdx.x;
    const int lane = t & 63, w = t >> 6;
    const int lm = lane & 15, lg = lane >> 4;
    const int g = blockIdx.x;                 // (b,h) group -> XCD locality
    const int h = g & 15, b = g >> 4;
    const int qt = (int)gridDim.y - 1 - (int)blockIdx.y;   // LPT: big blocks first
    const int kvh = h >> 1;
    const int q0b = qt * 64;
    const int q0w = q0b + w * 16;

    const unsigned short* qbase = qg + (size_t)(b * S_ + q0w + lm) * qld + h * HD_;
    bf16x8 qf[4];
    #pragma unroll
    for (int kk = 0; kk < 4; ++kk)
        qf[kk] = *reinterpret_cast<const bf16x8*>(qbase + kk * 32 + lg * 8);

    f32x4 acc[8];
    #pragma unroll
    for (int i = 0; i < 8; ++i) acc[i] = (f32x4){0.f, 0.f, 0.f, 0.f};
    float m = -3e38f, l = 0.f;

    const int nt = 2 * qt + 2;
    const int skv = t >> 3, sd8 = t & 7;   // K staging coords
    const int vd = t >> 1, vseg = t & 1;   // V staging coords
    const unsigned short* kgb = kg + (size_t)b * S_ * kld + kvh * HD_;
    const unsigned short* vgb = vtg + (size_t)(kvh * HD_) * (B_ * S_) + (size_t)b * S_;

    uint4 kr0, kr1, vr0, vr1;
    auto LOADR = [&](int kt) {
        const int kv0 = kt * KVB;
        const unsigned short* ksrc = kgb + (size_t)(kv0 + skv) * kld + sd8 * 16;
        kr0 = *reinterpret_cast<const uint4*>(ksrc);
        kr1 = *reinterpret_cast<const uint4*>(ksrc + 8);
        const unsigned short* vsrc = vgb + (size_t)vd * (B_ * S_) + kv0 + vseg * 16;
        vr0 = *reinterpret_cast<const uint4*>(vsrc);
        vr1 = *reinterpret_cast<const uint4*>(vsrc + 8);
    };
    auto WRITELDS = [&](int bufi) {
        char* kd = klds + bufi * 8192 + skv * 256;
        const int sw = (skv & 7) << 4;
        *reinterpret_cast<uint4*>(kd + ((sd8 * 32) ^ sw)) = kr0;
        *reinterpret_cast<uint4*>(kd + ((sd8 * 32 + 16) ^ sw)) = kr1;
        char* vdst = vtlds + bufi * 9216 + vd * 72 + vseg * 32;
        *reinterpret_cast<uint2*>(vdst)      = make_uint2(vr0.x, vr0.y);
        *reinterpret_cast<uint2*>(vdst + 8)  = make_uint2(vr0.z, vr0.w);
        *reinterpret_cast<uint2*>(vdst + 16) = make_uint2(vr1.x, vr1.y);
        *reinterpret_cast<uint2*>(vdst + 24) = make_uint2(vr1.z, vr1.w);
    };

    LOADR(0);
    WRITELDS(0);
    __syncthreads();

    for (int kt = 0; kt < nt; ++kt) {
        const int kv0 = kt * KVB;
        const int bufi = kt & 1;
        const bool havenext = (kt + 1 < nt);
        if (havenext) LOADR(kt + 1);
        if (kv0 <= q0w + 15) {
            f32x4 st[2];
            st[0] = (f32x4){0.f, 0.f, 0.f, 0.f};
            st[1] = (f32x4){0.f, 0.f, 0.f, 0.f};
            #pragma unroll
            for (int sub = 0; sub < 2; ++sub) {
                const int kvl = sub * 16 + lm;
                const char* krow = klds + bufi * 8192 + kvl * 256;
                const int sw = (kvl & 7) << 4;
                #pragma unroll
                for (int kk = 0; kk < 4; ++kk) {
                    const bf16x8 kf = *reinterpret_cast<const bf16x8*>(krow + ((kk * 64 + lg * 16) ^ sw));
                    st[sub] = __builtin_amdgcn_mfma_f32_16x16x32_bf16(kf, qf[kk], st[sub], 0, 0, 0);
                }
            }
            if (kv0 + KVB - 1 > q0w) {
                const int qa = q0w + lm;
                #pragma unroll
                for (int sub = 0; sub < 2; ++sub)
                    #pragma unroll
                    for (int r = 0; r < 4; ++r)
                        if (kv0 + sub * 16 + lg * 4 + r > qa) st[sub][r] = -3e38f;
            }
            float pmax = st[0][0];
            #pragma unroll
            for (int r = 1; r < 4; ++r) pmax = fmaxf(pmax, st[0][r]);
            #pragma unroll
            for (int r = 0; r < 4; ++r) pmax = fmaxf(pmax, st[1][r]);
            pmax = fmaxf(pmax, __shfl_xor(pmax, 16));
            pmax = fmaxf(pmax, __shfl_xor(pmax, 32));
            if (__any(pmax - m > 1.0f)) {       // defer-max (T13), log2 units
                const float mn = fmaxf(pmax, m);
                const float corr = exp2f(m - mn);
                l *= corr;
                #pragma unroll
                for (int i = 0; i < 8; ++i) acc[i] *= corr;
                m = mn;
            }
            float p[8];
            #pragma unroll
            for (int sub = 0; sub < 2; ++sub)
                #pragma unroll
                for (int r = 0; r < 4; ++r)
                    p[sub * 4 + r] = exp2f(st[sub][r] - m);   // log2 domain: no mul
            float ps = (p[0] + p[1]) + (p[2] + p[3]) + (p[4] + p[5]) + (p[6] + p[7]);
            ps += __shfl_xor(ps, 16);
            ps += __shfl_xor(ps, 32);
            l += ps;
            bf16x4 pb[2];
            #pragma unroll
            for (int sub = 0; sub < 2; ++sub) {
                union { unsigned int u[2]; bf16x4 v; } pk;
                pk.u[0] = cvtpk_bf16(p[sub * 4 + 0], p[sub * 4 + 1]);
                pk.u[1] = cvtpk_bf16(p[sub * 4 + 2], p[sub * 4 + 3]);
                pb[sub] = pk.v;
            }
            #pragma unroll
            for (int sub = 0; sub < 2; ++sub) {
                const char* vb2 = vtlds + bufi * 9216 + sub * 32 + lg * 8;
                #pragma unroll
                for (int db = 0; db < 8; ++db) {
                    const bf16x4 vf = *reinterpret_cast<const bf16x4*>(vb2 + (db * 16 + lm) * 72);
                    acc[db] = pv_mfma(vf, pb[sub], acc[db]);
                }
            }
        }
        if (havenext) WRITELDS((kt + 1) & 1);
        __syncthreads();
    }
    const float inv = 1.0f / l;
    unsigned short* ob = out + (size_t)(b * S_ + q0w + lm) * qld + h * HD_ + lg * 4;
    #pragma unroll
    for (int db = 0; db < 8; ++db) {
        uint2 o2;
        o2.x = cvtpk_bf16(acc[db][0] * inv, acc[db][1] * inv);
        o2.y = cvtpk_bf16(acc[db][2] * inv, acc[db][3] * inv);
        *reinterpret_cast<uint2*>(ob + db * 16) = o2;
    }
}

// ---------------- silu(g12[:, :3072]) * g12[:, 3072:] -> g12[:, :3072] in place ----------
__global__ __launch_bounds__(256)
void silu_mul_kernel(unsigned short* __restrict__ g, int n4) {
    const int i = blockIdx.x * 256 + threadIdx.x;
    if (i >= n4) return;
    const int r = i / (FF_ / 4);
    const int c = (i - r * (FF_ / 4)) * 4;
    const size_t off = (size_t)r * (2 * FF_) + c;
    const uint2 a = *reinterpret_cast<const uint2*>(g + off);
    const uint2 bv = *reinterpret_cast<const uint2*>(g + off + FF_);
    const unsigned int au[2] = {a.x, a.y}, bu[2] = {bv.x, bv.y};
    unsigned int rr[2];
    #pragma unroll
    for (int j = 0; j < 2; j++) {
        const float a0 = bf2f((unsigned short)(au[j] & 0xffff));
        const float a1 = bf2f((unsigned short)(au[j] >> 16));
        const float b0 = bf2f((unsigned short)(bu[j] & 0xffff));
        const float b1 = bf2f((unsigned short)(bu[j] >> 16));
        const float s0 = a0 / (1.f + __expf(-a0)) * b0;
        const float s1 = a1 / (1.f + __expf(-a1)) * b1;
        rr[j] = ((unsigned int)f2bf(s1) << 16) | (unsigned int)f2bf(s0);
    }
    *reinterpret_cast<uint2*>(g + off) = make_uint2(rr[0], rr[1]);
}

extern "C" void kernel_launch(void* const* d_in, const int* in_sizes, int n_in,
                              void* d_out, int out_size, void* d_ws, size_t ws_size,
                              hipStream_t stream) {
    const float* x    = (const float*)d_in[0];
    const float* cosb = (const float*)d_in[2];
    const float* sinb = (const float*)d_in[3];
    const float* wq   = (const float*)d_in[4];
    const float* wk   = (const float*)d_in[5];
    const float* wv   = (const float*)d_in[6];
    const float* wo   = (const float*)d_in[7];
    const float* fc1  = (const float*)d_in[8];
    const float* fc2  = (const float*)d_in[9];
    const float* fc3  = (const float*)d_in[10];
    const float* n1s  = (const float*)d_in[11];
    const float* n2s  = (const float*)d_in[12];
    const float* qns  = (const float*)d_in[13];
    const float* kns  = (const float*)d_in[14];

    char* ws = (char*)d_ws;
    const int M = B_ * S_;  // 4096
    float* outf = (float*)d_out;
    const float CS = 0.12752409731504826f;   // (1/sqrt(128)) * log2(e)

    unsigned short* h     = (unsigned short*)(ws);
    unsigned short* qkvb  = (unsigned short*)(ws + 8388608);
    unsigned short* vtb   = (unsigned short*)(ws + 41943040);
    unsigned short* g12   = (unsigned short*)(ws + 8388608);
    float*          x2    = (float*)(ws + 58720256);
    unsigned short* wqkvt = (unsigned short*)(ws + 75497472);
    unsigned short* wot   = (unsigned short*)(ws + 83886080);
    unsigned short* f12t  = (unsigned short*)(ws + 88080384);
    unsigned short* f3t   = (unsigned short*)(ws + 100663296);

    WTDesc wd;
    wd.src[0] = wq;  wd.dst[0] = wqkvt;                         wd.K[0] = D_;       wd.N[0] = 2048;
    wd.src[1] = wk;  wd.dst[1] = wqkvt + (size_t)2048 * 1024;   wd.K[1] = D_;       wd.N[1] = 1024;
    wd.src[2] = wv;  wd.dst[2] = wqkvt + (size_t)3072 * 1024;   wd.K[2] = D_;       wd.N[2] = 1024;
    wd.src[3] = wo;  wd.dst[3] = wot;                           wd.K[3] = H_ * HD_; wd.N[3] = D_;
    wd.src[4] = fc1; wd.dst[4] = f12t;                          wd.K[4] = D_;       wd.N[4] = FF_;
    wd.src[5] = fc2; wd.dst[5] = f12t + (size_t)3072 * 1024;    wd.K[5] = D_;       wd.N[5] = FF_;
    wd.src[6] = fc3; wd.dst[6] = f3t;                           wd.K[6] = FF_;      wd.N[6] = D_;
    wd.start[0] = 0;
    for (int i = 0; i < 7; ++i)
        wd.start[i + 1] = wd.start[i] + (wd.K[i] / 32) * (wd.N[i] / 32);
    wtrans_all_kernel<<<wd.start[7], 256, 0, stream>>>(wd);

    rmsnorm_kernel<<<M, 256, 0, stream>>>(x, n1s, h);
    gemm256<<<(M / 256) * (4096 / 256), 512, 0, stream>>>(h, wqkvt, qkvb, M, 4096, D_, M / 256);
    vtrans_kernel<<<dim3(M / 32, 1024 / 32), 256, 0, stream>>>(qkvb + 3072, vtb);
    qknorm_rope_kernel<<<dim3(M, H_), 128, 0, stream>>>(qkvb, qns, cosb, sinb, 4096, CS);
    qknorm_rope_kernel<<<dim3(M, KV_), 128, 0, stream>>>(qkvb + 2048, kns, cosb, sinb, 4096, 1.0f);
    fattn_kernel<<<dim3(H_ * B_, S_ / 64), 256, 0, stream>>>(qkvb, qkvb + 2048, vtb, qkvb, 4096, 4096);
    gemm_bt<1><<<dim3(M / 128, D_ / 128), 256, 0, stream>>>(qkvb, wot, x2, x, M, D_, H_ * HD_, 4096);
    rmsnorm_kernel<<<M, 256, 0, stream>>>(x2, n2s, h);
    gemm256<<<(M / 256) * (6144 / 256), 512, 0, stream>>>(h, f12t, g12, M, 6144, D_, M / 256);
    silu_mul_kernel<<<(M * FF_ / 4 + 255) / 256, 256, 0, stream>>>(g12, M * FF_ / 4);
    gemm_bt<1><<<dim3(M / 128, D_ / 128), 256, 0, stream>>>(g12, f3t, outf, x2, M, D_, FF_, 2 * FF_);
}

// Round 19
// 388.946 us; speedup vs baseline: 1.0090x; 1.0090x over previous
//
#include <hip/hip_runtime.h>

#define B_  2
#define S_  2048
#define D_  1024
#define H_  16
#define KV_ 8
#define HD_ 128
#define FF_ 3072
#define KVB 32

typedef short bf16x8 __attribute__((ext_vector_type(8)));
typedef short bf16x4 __attribute__((ext_vector_type(4)));
typedef float f32x4 __attribute__((ext_vector_type(4)));

__device__ __forceinline__ float bf2f(unsigned short u) {
    union { float f; unsigned int i; } c; c.i = ((unsigned int)u) << 16; return c.f;
}
__device__ __forceinline__ unsigned short f2bf(float f) {
    union { float f; unsigned int i; } c; c.f = f;
    unsigned int r = c.i + 0x7fffu + ((c.i >> 16) & 1u);
    return (unsigned short)(r >> 16);
}
__device__ __forceinline__ unsigned int cvtpk_bf16(float lo, float hi) {
    unsigned int r;
    asm("v_cvt_pk_bf16_f32 %0, %1, %2" : "=v"(r) : "v"(lo), "v"(hi));
    return r;
}

__device__ __forceinline__ void gload_lds16(const unsigned short* g, char* ldsbase) {
    __builtin_amdgcn_global_load_lds(
        (const __attribute__((address_space(1))) unsigned int*)g,
        (__attribute__((address_space(3))) unsigned int*)ldsbase, 16, 0, 0);
}

__device__ __forceinline__ f32x4 pv_mfma(bf16x4 a, bf16x4 b, f32x4 c) {
#if __has_builtin(__builtin_amdgcn_mfma_f32_16x16x16bf16_1k)
    return __builtin_amdgcn_mfma_f32_16x16x16bf16_1k(a, b, c, 0, 0, 0);
#elif __has_builtin(__builtin_amdgcn_mfma_f32_16x16x16_bf16)
    return __builtin_amdgcn_mfma_f32_16x16x16_bf16(a, b, c, 0, 0, 0);
#else
    f32x4 d;
    asm("v_mfma_f32_16x16x16_bf16 %0, %1, %2, %3" : "=v"(d) : "v"(a), "v"(b), "v"(c));
    return d;
#endif
}

// ---------------- rmsnorm: fp32 in -> bf16 out, D=1024, one block per row ----------------
__global__ __launch_bounds__(256)
void rmsnorm_kernel(const float* __restrict__ in, const float* __restrict__ scale,
                    unsigned short* __restrict__ out) {
    const int row = blockIdx.x;
    const int t = threadIdx.x;
    const float4 v = *reinterpret_cast<const float4*>(in + (size_t)row * D_ + t * 4);
    float s = v.x * v.x + v.y * v.y + v.z * v.z + v.w * v.w;
    #pragma unroll
    for (int o = 32; o; o >>= 1) s += __shfl_down(s, o);
    __shared__ float red[4];
    const int lane = t & 63, wid = t >> 6;
    if (lane == 0) red[wid] = s;
    __syncthreads();
    s = red[0] + red[1] + red[2] + red[3];
    const float rn = rsqrtf(s * (1.0f / D_) + 1e-6f);
    const float4 sc = *reinterpret_cast<const float4*>(scale + t * 4);
    unsigned short o4[4];
    o4[0] = f2bf(v.x * rn * sc.x);
    o4[1] = f2bf(v.y * rn * sc.y);
    o4[2] = f2bf(v.z * rn * sc.z);
    o4[3] = f2bf(v.w * rn * sc.w);
    *reinterpret_cast<ushort4*>(out + (size_t)row * D_ + t * 4) =
        *reinterpret_cast<ushort4*>(o4);
}

// ---------------- batched weight transpose: 7 weights, one launch ----------------
// mode 0: Wt[n][k].  mode 1/2: GLU interleave -> row (n>>7)*256 + (mode==2)*128 + (n&127).
struct WTDesc {
    const float* src[7];
    unsigned short* dst[7];
    int K[7];
    int N[7];
    int mode[7];
    int start[8];
};

__global__ __launch_bounds__(256)
void wtrans_all_kernel(WTDesc d) {
    __shared__ float tile[32][33];
    const int blk = blockIdx.x;
    int i = 0;
    #pragma unroll
    for (int j = 0; j < 7; ++j) if (blk >= d.start[j + 1]) i = j + 1;
    const int local = blk - d.start[i];
    const int K = d.K[i], N = d.N[i];
    const int mode = d.mode[i];
    const int nkt = K >> 5;
    const int kt = (local % nkt) * 32, nt = (local / nkt) * 32;
    const float* W = d.src[i];
    unsigned short* Wt = d.dst[i];
    const int t = threadIdx.x;
    {
        const int r = t >> 3, c4 = (t & 7) * 4;
        const float4 v = *reinterpret_cast<const float4*>(W + (size_t)(kt + r) * N + nt + c4);
        tile[r][c4] = v.x; tile[r][c4 + 1] = v.y; tile[r][c4 + 2] = v.z; tile[r][c4 + 3] = v.w;
    }
    __syncthreads();
    {
        const int n = t >> 3, k4 = (t & 7) * 4;
        int R = nt + n;
        if (mode) R = (R >> 7) * 256 + ((mode == 2) ? 128 : 0) + (R & 127);
        unsigned short o[4];
        #pragma unroll
        for (int q = 0; q < 4; q++) o[q] = f2bf(tile[k4 + q][n]);
        *reinterpret_cast<ushort4*>(Wt + (size_t)R * K + kt + k4) =
            *reinterpret_cast<ushort4*>(o);
    }
}

// ---------------- V transpose: vin[m][n] (ld 4096) -> vt[n][m] (ld 4096), bf16 ----------
__global__ __launch_bounds__(256)
void vtrans_kernel(const unsigned short* __restrict__ vin, unsigned short* __restrict__ vt) {
    __shared__ unsigned short tile[32][36];
    const int t = threadIdx.x;
    const int mt = blockIdx.x * 32, nt = blockIdx.y * 32;
    {
        const int r = t >> 3, c4 = (t & 7) * 4;
        *reinterpret_cast<ushort4*>(&tile[r][c4]) =
            *reinterpret_cast<const ushort4*>(vin + (size_t)(mt + r) * 4096 + nt + c4);
    }
    __syncthreads();
    {
        const int n = t >> 3, m4 = (t & 7) * 4;
        unsigned short o[4];
        #pragma unroll
        for (int q = 0; q < 4; q++) o[q] = tile[m4 + q][n];
        *reinterpret_cast<ushort4*>(vt + (size_t)(nt + n) * 4096 + mt + m4) =
            *reinterpret_cast<ushort4*>(o);
    }
}

// =============== 256^2 GEMM, 2-phase counted-vmcnt pipeline (verified round 8) ===========
// GLU=0: C[M][N] bf16.  GLU=1: B is interleaved [fc1|fc2] fused weight; epilogue computes
// silu(acc_fc1)*acc_fc2 via LDS exchange and writes gated [M][N/2] bf16 (epilogue-only
// change; K-loop byte-identical).
template<int GLU>
__global__ __launch_bounds__(512, 2)
void gemm256(const unsigned short* __restrict__ A, const unsigned short* __restrict__ Bt,
             unsigned short* __restrict__ C, int M, int N, int K, int nm) {
    __shared__ __align__(16) char lds[131072];
    const int tid = threadIdx.x;
    const int lane = tid & 63, w = tid >> 6;
    const int lm = lane & 15, lg = lane >> 4;
    const int wr = w >> 2, wc = w & 3;
    const int nwg = gridDim.x;
    const int cpx = nwg >> 3;                         // nwg % 8 == 0 (caller guarantees)
    const int bid = blockIdx.x;
    const int swz = (bid & 7) * cpx + (bid >> 3);     // bijective XCD swizzle
    const int m0 = (swz % nm) * 256;
    const int n0 = (swz / nm) * 256;

    f32x4 acc[8][4];
    #pragma unroll
    for (int i = 0; i < 8; ++i)
        #pragma unroll
        for (int j = 0; j < 4; ++j) acc[i][j] = (f32x4){0.f, 0.f, 0.f, 0.f};

    const int srow = tid >> 3;                                     // 0..63
    const int skel = ((tid & 7) * 8) ^ (((tid >> 5) & 1) << 4);    // pre-swizzled k-elem
    const int flip = ((lm >> 2) & 1) << 5;                         // read-side swizzle
    const int abase = (wr * 128 + lm) * 128 + ((lg * 16) ^ flip);
    const int bbase = (wc * 64 + lm) * 128 + ((lg * 16) ^ flip);

    auto part1 = [&](int kt, int d) {   // B0,B1,B2,B3,A0,A2 — issue order pinned
        const unsigned short* ga = A + (size_t)(m0 + srow) * K + kt * 64 + skel;
        const unsigned short* gb = Bt + (size_t)(n0 + srow) * K + kt * 64 + skel;
        char* la = lds + d * 65536 + (w << 10);
        char* lb = la + 32768;
        gload_lds16(gb,                      lb);
        gload_lds16(gb + (size_t)64 * K,     lb + 8192);
        gload_lds16(gb + (size_t)128 * K,    lb + 16384);
        gload_lds16(gb + (size_t)192 * K,    lb + 24576);
        gload_lds16(ga,                      la);
        gload_lds16(ga + (size_t)128 * K,    la + 16384);
    };
    auto part2 = [&](int kt, int d) {   // A1,A3
        const unsigned short* ga = A + (size_t)(m0 + srow) * K + kt * 64 + skel;
        char* la = lds + d * 65536 + (w << 10);
        gload_lds16(ga + (size_t)64 * K,     la + 8192);
        gload_lds16(ga + (size_t)192 * K,    la + 24576);
    };

    part1(0, 0);
    part2(0, 0);
    asm volatile("s_waitcnt vmcnt(0)" ::: "memory");
    __builtin_amdgcn_s_barrier();

    const int ntile = K >> 6;
    for (int kt = 0; kt < ntile; ++kt) {
        const int d = kt & 1;
        const bool pf = (kt + 1 < ntile);
        const char* Ar = lds + d * 65536;
        const char* Br = Ar + 32768;
        bf16x8 bb[4][2];
        #pragma unroll
        for (int nf = 0; nf < 4; ++nf)
            #pragma unroll
            for (int s = 0; s < 2; ++s)
                bb[nf][s] = *reinterpret_cast<const bf16x8*>(Br + bbase + nf * 2048 + s * 64);
        bf16x8 aH[4][2];
        #pragma unroll
        for (int f = 0; f < 4; ++f)
            #pragma unroll
            for (int s = 0; s < 2; ++s)
                aH[f][s] = *reinterpret_cast<const bf16x8*>(Ar + abase + f * 2048 + s * 64);
        if (pf) part1(kt + 1, d ^ 1);
        __builtin_amdgcn_s_setprio(1);
        #pragma unroll
        for (int f = 0; f < 4; ++f)
            #pragma unroll
            for (int nf = 0; nf < 4; ++nf)
                #pragma unroll
                for (int s = 0; s < 2; ++s)
                    acc[f][nf] = __builtin_amdgcn_mfma_f32_16x16x32_bf16(
                        aH[f][s], bb[nf][s], acc[f][nf], 0, 0, 0);
        __builtin_amdgcn_s_setprio(0);
        if (pf) asm volatile("s_waitcnt vmcnt(6)" ::: "memory");
        else    asm volatile("s_waitcnt vmcnt(0)" ::: "memory");
        __builtin_amdgcn_s_barrier();
        #pragma unroll
        for (int f = 0; f < 4; ++f)
            #pragma unroll
            for (int s = 0; s < 2; ++s)
                aH[f][s] = *reinterpret_cast<const bf16x8*>(Ar + abase + 8192 + f * 2048 + s * 64);
        if (pf) part2(kt + 1, d ^ 1);
        __builtin_amdgcn_s_setprio(1);
        #pragma unroll
        for (int f = 0; f < 4; ++f)
            #pragma unroll
            for (int nf = 0; nf < 4; ++nf)
                #pragma unroll
                for (int s = 0; s < 2; ++s)
                    acc[4 + f][nf] = __builtin_amdgcn_mfma_f32_16x16x32_bf16(
                        aH[f][s], bb[nf][s], acc[4 + f][nf], 0, 0, 0);
        __builtin_amdgcn_s_setprio(0);
        if (pf) {
            asm volatile("s_waitcnt vmcnt(2)" ::: "memory");
            __builtin_amdgcn_s_barrier();
        }
    }

    if (GLU == 0) {
        #pragma unroll
        for (int mf = 0; mf < 8; ++mf)
            #pragma unroll
            for (int nf = 0; nf < 4; ++nf)
                #pragma unroll
                for (int r = 0; r < 4; ++r)
                    C[(size_t)(m0 + wr * 128 + mf * 16 + lg * 4 + r) * N +
                      (n0 + wc * 64 + nf * 16 + lm)] = f2bf(acc[mf][nf][r]);
    } else {
        // cols [0,128) of tile = fc1 (wc 0,1); cols [128,256) = fc2 (wc 2,3)
        __syncthreads();                    // all waves done reading LDS K-tiles
        float (*xch)[128] = reinterpret_cast<float(*)[128]>(lds);   // [256][128] fp32
        if (wc < 2) {
            #pragma unroll
            for (int mf = 0; mf < 8; ++mf)
                #pragma unroll
                for (int nf = 0; nf < 4; ++nf)
                    #pragma unroll
                    for (int r = 0; r < 4; ++r)
                        xch[wr * 128 + mf * 16 + lg * 4 + r][wc * 64 + nf * 16 + lm] =
                            acc[mf][nf][r];
        }
        __syncthreads();
        if (wc >= 2) {
            const int nblk = swz / nm;
            #pragma unroll
            for (int mf = 0; mf < 8; ++mf)
                #pragma unroll
                for (int nf = 0; nf < 4; ++nf)
                    #pragma unroll
                    for (int r = 0; r < 4; ++r) {
                        const int row = wr * 128 + mf * 16 + lg * 4 + r;
                        const int col = (wc - 2) * 64 + nf * 16 + lm;
                        const float g1 = xch[row][col];
                        const float s = g1 / (1.f + __expf(-g1)) * acc[mf][nf][r];
                        C[(size_t)(m0 + row) * FF_ + nblk * 128 + col] = f2bf(s);
                    }
        }
    }
}

// ---------------- m97-structure GEMM: C[M,N] = A(bf16 [M][lda]) @ Bt(bf16 [N][K])^T ------
template<int EPI>
__global__ __launch_bounds__(256)
void gemm_bt(const unsigned short* __restrict__ A, const unsigned short* __restrict__ Bt,
             void* __restrict__ Cout, const float* __restrict__ resid,
             int M, int N, int K, int lda) {
    __shared__ __align__(16) char sm[16384];
    const int t = threadIdx.x;
    const int lane = t & 63, w = t >> 6;
    const int m0 = blockIdx.x * 128, n0 = blockIdx.y * 128;
    const int wr = w >> 1, wc = w & 1;
    const int lm = lane & 15, lg = lane >> 4;

    f32x4 acc[4][4];
    #pragma unroll
    for (int i = 0; i < 4; i++)
        #pragma unroll
        for (int j = 0; j < 4; j++) acc[i][j] = (f32x4){0.f, 0.f, 0.f, 0.f};

    const int row0 = t >> 2, kseg = (t & 3) * 8;
    const unsigned short* Ab = A + (size_t)(m0 + row0) * lda + kseg;
    const unsigned short* Bb = Bt + (size_t)(n0 + row0) * K + kseg;
    const size_t rstepA = (size_t)64 * lda;
    const size_t rstepB = (size_t)64 * K;
    char* ldsA = sm + w * 1024;
    char* ldsB = sm + 8192 + w * 1024;

    for (int k0 = 0; k0 < K; k0 += 32) {
        gload_lds16(Ab + k0, ldsA);
        gload_lds16(Ab + rstepA + k0, ldsA + 4096);
        gload_lds16(Bb + k0, ldsB);
        gload_lds16(Bb + rstepB + k0, ldsB + 4096);
        __syncthreads();
        bf16x8 aF[4], bF[4];
        #pragma unroll
        for (int i = 0; i < 4; i++)
            aF[i] = *reinterpret_cast<const bf16x8*>(sm + (wr * 64 + i * 16 + lm) * 64 + lg * 16);
        #pragma unroll
        for (int j = 0; j < 4; j++)
            bF[j] = *reinterpret_cast<const bf16x8*>(sm + 8192 + (wc * 64 + j * 16 + lm) * 64 + lg * 16);
        #pragma unroll
        for (int i = 0; i < 4; i++)
            #pragma unroll
            for (int j = 0; j < 4; j++)
                acc[i][j] = __builtin_amdgcn_mfma_f32_16x16x32_bf16(aF[i], bF[j], acc[i][j], 0, 0, 0);
        __syncthreads();
    }

    #pragma unroll
    for (int i = 0; i < 4; i++) {
        #pragma unroll
        for (int j = 0; j < 4; j++) {
            #pragma unroll
            for (int r = 0; r < 4; r++) {
                const int row = m0 + wr * 64 + i * 16 + lg * 4 + r;
                const int col = n0 + wc * 64 + j * 16 + lm;
                const size_t idx = (size_t)row * N + col;
                if (EPI == 0) {
                    reinterpret_cast<unsigned short*>(Cout)[idx] = f2bf(acc[i][j][r]);
                } else {
                    reinterpret_cast<float*>(Cout)[idx] = resid[idx] + acc[i][j][r];
                }
            }
        }
    }
}

// ---------------- per-head rmsnorm + rope, in-place, with output scale ----------------
__global__ __launch_bounds__(128)
void qknorm_rope_kernel(unsigned short* __restrict__ qk, const float* __restrict__ scale,
                        const float* __restrict__ cosb, const float* __restrict__ sinb,
                        int ld, float oscale) {
    const int row = blockIdx.x;
    const int head = blockIdx.y;
    const int s = row & (S_ - 1);
    const int t = threadIdx.x;
    unsigned short* p = qk + (size_t)row * ld + head * HD_;
    const float v = bf2f(p[t]);
    float ss = v * v;
    #pragma unroll
    for (int o = 32; o; o >>= 1) ss += __shfl_down(ss, o);
    __shared__ float red[2];
    __shared__ float vals[HD_];
    const int lane = t & 63, wid = t >> 6;
    if (lane == 0) red[wid] = ss;
    __syncthreads();
    ss = red[0] + red[1];
    const float rn = rsqrtf(ss * (1.0f / HD_) + 1e-6f);
    const float nv = v * rn * scale[t];
    vals[t] = nv;
    __syncthreads();
    const float rot = (t < 64) ? -vals[t + 64] : vals[t - 64];
    const float c = cosb[(size_t)s * HD_ + t];
    const float sn = sinb[(size_t)s * HD_ + t];
    p[t] = f2bf((nv * c + rot * sn) * oscale);
}

// ---------------- MFMA flash attention v3: VALU-diet (cvt_pk + log2-domain Q) ----------
__global__ __launch_bounds__(256)
void fattn_kernel(const unsigned short* __restrict__ qg,
                  const unsigned short* __restrict__ kg,
                  const unsigned short* __restrict__ vtg,
                  unsigned short* __restrict__ out, int qld, int kld) {
    __shared__ __align__(16) char klds[2 * 8192];    // [buf][32 rows x 256B], xor-swizzled
    __shared__ __align__(16) char vtlds[2 * 9216];   // [buf][128 rows x 72B pitch]
    const int t = threadIdx.x;
    const int lane = t & 63, w = t >> 6;
    const int lm = lane & 15, lg = lane >> 4;
    const int g = blockIdx.x;                 // (b,h) group -> XCD locality
    const int h = g & 15, b = g >> 4;
    const int qt = (int)gridDim.y - 1 - (int)blockIdx.y;   // LPT: big blocks first
    const int kvh = h >> 1;
    const int q0b = qt * 64;
    const int q0w = q0b + w * 16;

    const unsigned short* qbase = qg + (size_t)(b * S_ + q0w + lm) * qld + h * HD_;
    bf16x8 qf[4];
    #pragma unroll
    for (int kk = 0; kk < 4; ++kk)
        qf[kk] = *reinterpret_cast<const bf16x8*>(qbase + kk * 32 + lg * 8);

    f32x4 acc[8];
    #pragma unroll
    for (int i = 0; i < 8; ++i) acc[i] = (f32x4){0.f, 0.f, 0.f, 0.f};
    float m = -3e38f, l = 0.f;

    const int nt = 2 * qt + 2;
    const int skv = t >> 3, sd8 = t & 7;   // K staging coords
    const int vd = t >> 1, vseg = t & 1;   // V staging coords
    const unsigned short* kgb = kg + (size_t)b * S_ * kld + kvh * HD_;
    const unsigned short* vgb = vtg + (size_t)(kvh * HD_) * (B_ * S_) + (size_t)b * S_;

    uint4 kr0, kr1, vr0, vr1;
    auto LOADR = [&](int kt) {
        const int kv0 = kt * KVB;
        const unsigned short* ksrc = kgb + (size_t)(kv0 + skv) * kld + sd8 * 16;
        kr0 = *reinterpret_cast<const uint4*>(ksrc);
        kr1 = *reinterpret_cast<const uint4*>(ksrc + 8);
        const unsigned short* vsrc = vgb + (size_t)vd * (B_ * S_) + kv0 + vseg * 16;
        vr0 = *reinterpret_cast<const uint4*>(vsrc);
        vr1 = *reinterpret_cast<const uint4*>(vsrc + 8);
    };
    auto WRITELDS = [&](int bufi) {
        char* kd = klds + bufi * 8192 + skv * 256;
        const int sw = (skv & 7) << 4;
        *reinterpret_cast<uint4*>(kd + ((sd8 * 32) ^ sw)) = kr0;
        *reinterpret_cast<uint4*>(kd + ((sd8 * 32 + 16) ^ sw)) = kr1;
        char* vdst = vtlds + bufi * 9216 + vd * 72 + vseg * 32;
        *reinterpret_cast<uint2*>(vdst)      = make_uint2(vr0.x, vr0.y);
        *reinterpret_cast<uint2*>(vdst + 8)  = make_uint2(vr0.z, vr0.w);
        *reinterpret_cast<uint2*>(vdst + 16) = make_uint2(vr1.x, vr1.y);
        *reinterpret_cast<uint2*>(vdst + 24) = make_uint2(vr1.z, vr1.w);
    };

    LOADR(0);
    WRITELDS(0);
    __syncthreads();

    for (int kt = 0; kt < nt; ++kt) {
        const int kv0 = kt * KVB;
        const int bufi = kt & 1;
        const bool havenext = (kt + 1 < nt);
        if (havenext) LOADR(kt + 1);
        if (kv0 <= q0w + 15) {
            f32x4 st[2];
            st[0] = (f32x4){0.f, 0.f, 0.f, 0.f};
            st[1] = (f32x4){0.f, 0.f, 0.f, 0.f};
            #pragma unroll
            for (int sub = 0; sub < 2; ++sub) {
                const int kvl = sub * 16 + lm;
                const char* krow = klds + bufi * 8192 + kvl * 256;
                const int sw = (kvl & 7) << 4;
                #pragma unroll
                for (int kk = 0; kk < 4; ++kk) {
                    const bf16x8 kf = *reinterpret_cast<const bf16x8*>(krow + ((kk * 64 + lg * 16) ^ sw));
                    st[sub] = __builtin_amdgcn_mfma_f32_16x16x32_bf16(kf, qf[kk], st[sub], 0, 0, 0);
                }
            }
            if (kv0 + KVB - 1 > q0w) {
                const int qa = q0w + lm;
                #pragma unroll
                for (int sub = 0; sub < 2; ++sub)
                    #pragma unroll
                    for (int r = 0; r < 4; ++r)
                        if (kv0 + sub * 16 + lg * 4 + r > qa) st[sub][r] = -3e38f;
            }
            float pmax = st[0][0];
            #pragma unroll
            for (int r = 1; r < 4; ++r) pmax = fmaxf(pmax, st[0][r]);
            #pragma unroll
            for (int r = 0; r < 4; ++r) pmax = fmaxf(pmax, st[1][r]);
            pmax = fmaxf(pmax, __shfl_xor(pmax, 16));
            pmax = fmaxf(pmax, __shfl_xor(pmax, 32));
            if (__any(pmax - m > 1.0f)) {       // defer-max (T13), log2 units
                const float mn = fmaxf(pmax, m);
                const float corr = exp2f(m - mn);
                l *= corr;
                #pragma unroll
                for (int i = 0; i < 8; ++i) acc[i] *= corr;
                m = mn;
            }
            float p[8];
            #pragma unroll
            for (int sub = 0; sub < 2; ++sub)
                #pragma unroll
                for (int r = 0; r < 4; ++r)
                    p[sub * 4 + r] = exp2f(st[sub][r] - m);   // log2 domain: no mul
            float ps = (p[0] + p[1]) + (p[2] + p[3]) + (p[4] + p[5]) + (p[6] + p[7]);
            ps += __shfl_xor(ps, 16);
            ps += __shfl_xor(ps, 32);
            l += ps;
            bf16x4 pb[2];
            #pragma unroll
            for (int sub = 0; sub < 2; ++sub) {
                union { unsigned int u[2]; bf16x4 v; } pk;
                pk.u[0] = cvtpk_bf16(p[sub * 4 + 0], p[sub * 4 + 1]);
                pk.u[1] = cvtpk_bf16(p[sub * 4 + 2], p[sub * 4 + 3]);
                pb[sub] = pk.v;
            }
            #pragma unroll
            for (int sub = 0; sub < 2; ++sub) {
                const char* vb2 = vtlds + bufi * 9216 + sub * 32 + lg * 8;
                #pragma unroll
                for (int db = 0; db < 8; ++db) {
                    const bf16x4 vf = *reinterpret_cast<const bf16x4*>(vb2 + (db * 16 + lm) * 72);
                    acc[db] = pv_mfma(vf, pb[sub], acc[db]);
                }
            }
        }
        if (havenext) WRITELDS((kt + 1) & 1);
        __syncthreads();
    }
    const float inv = 1.0f / l;
    unsigned short* ob = out + (size_t)(b * S_ + q0w + lm) * qld + h * HD_ + lg * 4;
    #pragma unroll
    for (int db = 0; db < 8; ++db) {
        uint2 o2;
        o2.x = cvtpk_bf16(acc[db][0] * inv, acc[db][1] * inv);
        o2.y = cvtpk_bf16(acc[db][2] * inv, acc[db][3] * inv);
        *reinterpret_cast<uint2*>(ob + db * 16) = o2;
    }
}

extern "C" void kernel_launch(void* const* d_in, const int* in_sizes, int n_in,
                              void* d_out, int out_size, void* d_ws, size_t ws_size,
                              hipStream_t stream) {
    const float* x    = (const float*)d_in[0];
    const float* cosb = (const float*)d_in[2];
    const float* sinb = (const float*)d_in[3];
    const float* wq   = (const float*)d_in[4];
    const float* wk   = (const float*)d_in[5];
    const float* wv   = (const float*)d_in[6];
    const float* wo   = (const float*)d_in[7];
    const float* fc1  = (const float*)d_in[8];
    const float* fc2  = (const float*)d_in[9];
    const float* fc3  = (const float*)d_in[10];
    const float* n1s  = (const float*)d_in[11];
    const float* n2s  = (const float*)d_in[12];
    const float* qns  = (const float*)d_in[13];
    const float* kns  = (const float*)d_in[14];

    char* ws = (char*)d_ws;
    const int M = B_ * S_;  // 4096
    float* outf = (float*)d_out;
    const float CS = 0.12752409731504826f;   // (1/sqrt(128)) * log2(e)

    unsigned short* h     = (unsigned short*)(ws);
    unsigned short* qkvb  = (unsigned short*)(ws + 8388608);
    unsigned short* vtb   = (unsigned short*)(ws + 41943040);
    unsigned short* gated = (unsigned short*)(ws + 8388608);   // [4096][3072] bf16, aliases qkvb
    float*          x2    = (float*)(ws + 58720256);
    unsigned short* wqkvt = (unsigned short*)(ws + 75497472);
    unsigned short* wot   = (unsigned short*)(ws + 83886080);
    unsigned short* f12g  = (unsigned short*)(ws + 88080384);  // GLU-interleaved [6144][1024]
    unsigned short* f3t   = (unsigned short*)(ws + 100663296);

    WTDesc wd;
    wd.src[0] = wq;  wd.dst[0] = wqkvt;                       wd.K[0] = D_;       wd.N[0] = 2048; wd.mode[0] = 0;
    wd.src[1] = wk;  wd.dst[1] = wqkvt + (size_t)2048 * 1024; wd.K[1] = D_;       wd.N[1] = 1024; wd.mode[1] = 0;
    wd.src[2] = wv;  wd.dst[2] = wqkvt + (size_t)3072 * 1024; wd.K[2] = D_;       wd.N[2] = 1024; wd.mode[2] = 0;
    wd.src[3] = wo;  wd.dst[3] = wot;                         wd.K[3] = H_ * HD_; wd.N[3] = D_;   wd.mode[3] = 0;
    wd.src[4] = fc1; wd.dst[4] = f12g;                        wd.K[4] = D_;       wd.N[4] = FF_;  wd.mode[4] = 1;
    wd.src[5] = fc2; wd.dst[5] = f12g;                        wd.K[5] = D_;       wd.N[5] = FF_;  wd.mode[5] = 2;
    wd.src[6] = fc3; wd.dst[6] = f3t;                         wd.K[6] = FF_;      wd.N[6] = D_;   wd.mode[6] = 0;
    wd.start[0] = 0;
    for (int i = 0; i < 7; ++i)
        wd.start[i + 1] = wd.start[i] + (wd.K[i] / 32) * (wd.N[i] / 32);
    wtrans_all_kernel<<<wd.start[7], 256, 0, stream>>>(wd);

    rmsnorm_kernel<<<M, 256, 0, stream>>>(x, n1s, h);
    gemm256<0><<<(M / 256) * (4096 / 256), 512, 0, stream>>>(h, wqkvt, qkvb, M, 4096, D_, M / 256);
    vtrans_kernel<<<dim3(M / 32, 1024 / 32), 256, 0, stream>>>(qkvb + 3072, vtb);
    qknorm_rope_kernel<<<dim3(M, H_), 128, 0, stream>>>(qkvb, qns, cosb, sinb, 4096, CS);
    qknorm_rope_kernel<<<dim3(M, KV_), 128, 0, stream>>>(qkvb + 2048, kns, cosb, sinb, 4096, 1.0f);
    fattn_kernel<<<dim3(H_ * B_, S_ / 64), 256, 0, stream>>>(qkvb, qkvb + 2048, vtb, qkvb, 4096, 4096);
    gemm_bt<1><<<dim3(M / 128, D_ / 128), 256, 0, stream>>>(qkvb, wot, x2, x, M, D_, H_ * HD_, 4096);
    rmsnorm_kernel<<<M, 256, 0, stream>>>(x2, n2s, h);
    // fused fc1+fc2 with GLU epilogue: gated[4096][3072] = silu(h@fc1) * (h@fc2)
    gemm256<1><<<(M / 256) * (6144 / 256), 512, 0, stream>>>(h, f12g, gated, M, 6144, D_, M / 256);
    gemm_bt<1><<<dim3(M / 128, D_ / 128), 256, 0, stream>>>(gated, f3t, outf, x2, M, D_, FF_, FF_);
}